// Round 7
// baseline (14059.363 us; speedup 1.0000x reference)
//
#include <hip/hip_runtime.h>

// liGRU (2-layer) on MI355X.
//   1. cast/split inputs to [hi|lo] bf16 along K (split-bf16 => ~fp32 accuracy)
//   2. gemm_bt: C[m,n] = sum_k A[m,k]*W[n,k] via mfma_f32_16x16x32_bf16, K'=2048
//   3. bn_inplace: BatchNorm over batch per (t,h); input biases cancel in BN,
//      recurrent biases folded into beta.
//   4. ligru_rec: persistent kernel, 64 WGs x 256 threads (4 waves, 1 WG/CU),
//      W in registers/AGPRs. SELF-VALIDATING TAGGED h exchange: each h value is
//      u32 = (bf16<<16)|tag; consumers spin on the data itself (LLC atomic
//      loads) — no flag RT, no producer drain on the critical path. Per-wave
//      read-flags only guard 2-buffer reuse (checked off-path). Per-layer
//      tagbase avoids stale-tag collisions across layers and graph replays.

typedef unsigned short u16;
typedef unsigned int   u32;
typedef unsigned long long u64;
typedef __attribute__((ext_vector_type(8))) short bf16x8;
typedef __attribute__((ext_vector_type(4))) float f32x4;
typedef __attribute__((ext_vector_type(2))) float f32x2;

#define TSTEPS 512
#define BATCH  32
#define HDIM   1024
#define MROWS  (TSTEPS * BATCH)   // 16384
#define KP     2048               // split-K (hi|lo concat)
#define NWG    64
#define HBUFN  (BATCH * 512)      // u64 per buffer (32 rows x 512 u64 = 1024 tagged u32)

__device__ __forceinline__ u16 f2bf(float f) {
  u32 u = __float_as_uint(f);
  return (u16)((u + 0x7FFFu + ((u >> 16) & 1u)) >> 16);  // RNE
}
__device__ __forceinline__ float bf2f(u16 h) {
  return __uint_as_float(((u32)h) << 16);
}

// ---------------- cast + split: fp32 [rows][1024] -> bf16 [rows][2048] = [hi|lo]
__global__ void cast_split(const float* __restrict__ src, u16* __restrict__ dst, int total) {
  int idx = blockIdx.x * 256 + threadIdx.x;
  if (idx >= total) return;
  int m = idx >> 10, k = idx & 1023;
  float v = src[idx];
  u16 hi = f2bf(v);
  u16 lo = f2bf(v - bf2f(hi));
  dst[(size_t)m * KP + k] = hi;
  dst[(size_t)m * KP + 1024 + k] = lo;
}

// ---------------- async global->LDS, 16B per lane
__device__ __forceinline__ void stage16(const u16* g, u16* l) {
  __builtin_amdgcn_global_load_lds((const __attribute__((address_space(1))) u32*)g,
                                   (__attribute__((address_space(3))) u32*)l, 16, 0, 0);
}

// ---------------- GEMM: C[m,n] = sum_k A[m,k] * W[n,k]   (A:[M][KP], W:[1024][KP])
__global__ __launch_bounds__(256) void gemm_bt(
    const u16* __restrict__ A,
    const u16* __restrict__ Wa, const u16* __restrict__ Wb,
    float* __restrict__ Ca, float* __restrict__ Cb) {
  constexpr int BK = 64;
  const u16* W = blockIdx.z ? Wb : Wa;
  float*     C = blockIdx.z ? Cb : Ca;
  const int m0 = blockIdx.y * 128;
  const int n0 = blockIdx.x * 128;
  __shared__ __align__(16) u16 As[128 * BK];
  __shared__ __align__(16) u16 Bs[128 * BK];
  const int tid  = threadIdx.x;
  const int lane = tid & 63;
  const int wv   = tid >> 6;
  const int wm   = wv >> 1, wn = wv & 1;
  const int srow = tid >> 3;
  const int scol = (tid & 7) * 8;
  const int frow = lane & 15;
  const int kcol = (lane >> 4) * 8;

  f32x4 z4 = {0.f, 0.f, 0.f, 0.f};
  f32x4 acc[4][4];
#pragma unroll
  for (int i = 0; i < 4; ++i)
#pragma unroll
    for (int j = 0; j < 4; ++j) acc[i][j] = z4;

  for (int k0 = 0; k0 < KP; k0 += BK) {
#pragma unroll
    for (int i = 0; i < 4; ++i)
      stage16(A + (size_t)(m0 + i * 32 + srow) * KP + k0 + scol, &As[(i * 32 + srow) * BK + scol]);
#pragma unroll
    for (int i = 0; i < 4; ++i)
      stage16(W + (size_t)(n0 + i * 32 + srow) * KP + k0 + scol, &Bs[(i * 32 + srow) * BK + scol]);
    __syncthreads();
#pragma unroll
    for (int kk = 0; kk < 2; ++kk) {
      bf16x8 av[4], bv[4];
#pragma unroll
      for (int i = 0; i < 4; ++i)
        av[i] = *(const bf16x8*)&As[(wm * 64 + i * 16 + frow) * BK + kk * 32 + kcol];
#pragma unroll
      for (int j = 0; j < 4; ++j)
        bv[j] = *(const bf16x8*)&Bs[(wn * 64 + j * 16 + frow) * BK + kk * 32 + kcol];
#pragma unroll
      for (int i = 0; i < 4; ++i)
#pragma unroll
        for (int j = 0; j < 4; ++j)
          acc[i][j] = __builtin_amdgcn_mfma_f32_16x16x32_bf16(av[i], bv[j], acc[i][j], 0, 0, 0);
    }
    __syncthreads();
  }
#pragma unroll
  for (int i = 0; i < 4; ++i)
#pragma unroll
    for (int j = 0; j < 4; ++j) {
      int n  = n0 + wn * 64 + j * 16 + (lane & 15);
      int mb = m0 + wm * 64 + i * 16 + (lane >> 4) * 4;
#pragma unroll
      for (int r = 0; r < 4; ++r)
        C[(size_t)(mb + r) * HDIM + n] = acc[i][j][r];
    }
}

// ---------------- BatchNorm over batch axis, per (t,h); in-place; beta' = beta + b_rec
__global__ void bn_inplace(float* __restrict__ Pz, float* __restrict__ Ph,
                           const float* __restrict__ gz, const float* __restrict__ bz, const float* __restrict__ bhz,
                           const float* __restrict__ gh, const float* __restrict__ bh, const float* __restrict__ bhh) {
  float*       P    = blockIdx.y ? Ph  : Pz;
  const float* gam  = blockIdx.y ? gh  : gz;
  const float* bet  = blockIdx.y ? bh  : bz;
  const float* brec = blockIdx.y ? bhh : bhz;
  int idx = blockIdx.x * 256 + threadIdx.x;
  int h = idx & 1023;
  size_t base = (size_t)(idx >> 10) * (BATCH * HDIM) + h;
  float v[BATCH];
  float s = 0.f;
#pragma unroll
  for (int b = 0; b < BATCH; ++b) { v[b] = P[base + (size_t)b * HDIM]; s += v[b]; }
  float mean = s * (1.f / BATCH);
  float q = 0.f;
#pragma unroll
  for (int b = 0; b < BATCH; ++b) { float d = v[b] - mean; q += d * d; }
  float inv = rsqrtf(q * (1.f / BATCH) + 1e-5f) * gam[h];
  float add = bet[h] + brec[h];
#pragma unroll
  for (int b = 0; b < BATCH; ++b)
    P[base + (size_t)b * HDIM] = (v[b] - mean) * inv + add;
}

__global__ void init_bar(u32* flags) { flags[threadIdx.x] = 0; }  // <<<1,256>>>

// ---------------- persistent recurrence: 64 WGs x 256 threads (4 waves), 512 steps
// wave wv: half = wv>>1 (batch half), ksec = wv&1 (K half); each wave computes
// BOTH gates from one h-load set; W fragments in registers/AGPRs.
// h channel: hbuf[2][32][512] u64; each u64 = two tagged u32 (bf16<<16 | tag),
// tag = tagbase + state_index. Consumers spin-load + validate tags (LLC atomic
// loads) — detection IS data arrival. rflags[256] (per wave) only guard the
// distance-2 buffer reuse; their check is issued early and verified just
// before the h-store (normally satisfied one full step in advance).
__global__ __launch_bounds__(256, 1) void ligru_rec(
    const float* __restrict__ nxz, const float* __restrict__ nxh,
    const float* __restrict__ Whz, const float* __restrict__ Whh,
    const float* __restrict__ h0,
    u16*   __restrict__ hs_bf,   // layer-1 out: [16384][2048] split bf16; or null
    float* __restrict__ hs_f,    // layer-2 out: d_out x region; or null
    float* __restrict__ hlast,   // [32][1024]
    u64*   __restrict__ hbuf,    // [2][32][512] u64 tagged
    u32*   __restrict__ rflags,  // [256] per-wave read flags
    int tagbase) {
  const int g    = blockIdx.x;
  const int c0   = g * 16;
  const int tid  = threadIdx.x;
  const int lane = tid & 63;
  const int wv   = tid >> 6;      // 0..3
  const int half = wv >> 1;       // batch half
  const int ksec = wv & 1;        // K half
  const int r    = lane & 15;     // owned column index (B-frag row)
  const int ko   = lane >> 4;     // k sub-offset

  __shared__ float part[2][2][2][16][17];  // [gate][ksec][half][row][col]

  // ---- W fragments -> registers/AGPRs (one-time). Lane holds
  // W[c0+r][ksec*512 + ko*8 + kk*32 + 0..7], split hi/lo bf16.
  bf16x8 wz_hi[16], wz_lo[16], wh_hi[16], wh_lo[16];
  {
    const float* zrow = Whz + (size_t)(c0 + r) * HDIM;
    const float* hrow = Whh + (size_t)(c0 + r) * HDIM;
#pragma unroll
    for (int kk = 0; kk < 16; ++kk) {
      int kb = ksec * 512 + ko * 8 + kk * 32;
      f32x4 z0 = *(const f32x4*)(zrow + kb);
      f32x4 z1 = *(const f32x4*)(zrow + kb + 4);
      f32x4 h0v = *(const f32x4*)(hrow + kb);
      f32x4 h1v = *(const f32x4*)(hrow + kb + 4);
      bf16x8 zh, zl, hh, hl;
#pragma unroll
      for (int j = 0; j < 4; ++j) {
        u16 a = f2bf(z0[j]);  zh[j]   = (short)a;  zl[j]   = (short)f2bf(z0[j] - bf2f(a));
        u16 b = f2bf(z1[j]);  zh[4+j] = (short)b;  zl[4+j] = (short)f2bf(z1[j] - bf2f(b));
        u16 c = f2bf(h0v[j]); hh[j]   = (short)c;  hl[j]   = (short)f2bf(h0v[j] - bf2f(c));
        u16 d = f2bf(h1v[j]); hh[4+j] = (short)d;  hl[4+j] = (short)f2bf(h1v[j] - bf2f(d));
      }
      wz_hi[kk] = zh; wz_lo[kk] = zl; wh_hi[kk] = hh; wh_lo[kk] = hl;
    }
  }

  // ---- per-thread h state: bb = tid>>3 (batch), columns 2*cp, 2*cp+1
  const int bb = tid >> 3;
  const int cp = tid & 7;
  const int bh_ = bb >> 4, br_ = bb & 15;
  float hr0 = h0[(size_t)bb * HDIM + c0 + 2 * cp];
  float hr1 = h0[(size_t)bb * HDIM + c0 + 2 * cp + 1];
  {
    u32 t0 = (u32)tagbase;
    u32 lo = ((u32)f2bf(hr0) << 16) | t0;
    u32 hi = ((u32)f2bf(hr1) << 16) | t0;
    u64 w = ((u64)hi << 32) | (u64)lo;
    __hip_atomic_store(hbuf + (size_t)bb * 512 + g * 8 + cp, w,
                       __ATOMIC_RELAXED, __HIP_MEMORY_SCOPE_AGENT);  // buffer 0
  }
  // nx for t=0
  f32x2 nxz_c = *(const f32x2*)(nxz + (size_t)bb * HDIM + c0 + 2 * cp);
  f32x2 nxh_c = *(const f32x2*)(nxh + (size_t)bb * HDIM + c0 + 2 * cp);

  // consumer-side A-fragment base, in u64 units of a [32][512] u64 buffer
  const size_t hbase = (size_t)(half * 16 + r) * 512 + ksec * 256 + ko * 4;
  const u64* f64 = (const u64*)rflags;
  f32x4 z4 = {0.f, 0.f, 0.f, 0.f};

  for (int t = 0; t < TSTEPS; ++t) {
    const u64* hb  = hbuf + (size_t)(t & 1) * HBUFN;
    u64*       hbn = hbuf + (size_t)((t + 1) & 1) * HBUFN;
    const u32 tag  = (u32)(tagbase + t);
    const u64 tagpair = (u64)tag | ((u64)tag << 32);

    // ---- spin: load h(t) fragments, validate tags; retry until all match
    u64 hw[64];
    for (;;) {
#pragma unroll
      for (int i = 0; i < 64; ++i)
        hw[i] = __hip_atomic_load(hb + hbase + (i >> 2) * 16 + (i & 3),
                                  __ATOMIC_RELAXED, __HIP_MEMORY_SCOPE_AGENT);
      u64 acc = 0;
#pragma unroll
      for (int i = 0; i < 64; ++i)
        acc |= (hw[i] ^ tagpair) & 0x0000FFFF0000FFFFull;
      if (__all(acc == 0)) break;
    }

    // post read-flag (buffer-reuse guard), then issue the early rflag poll
    if (lane == 0)
      __hip_atomic_store(&rflags[g * 4 + wv], (u32)(t + 1),
                         __ATOMIC_RELAXED, __HIP_MEMORY_SCOPE_AGENT);
    u64 fa = __hip_atomic_load(f64 + lane * 2,     __ATOMIC_RELAXED, __HIP_MEMORY_SCOPE_AGENT);
    u64 fb = __hip_atomic_load(f64 + lane * 2 + 1, __ATOMIC_RELAXED, __HIP_MEMORY_SCOPE_AGENT);

    // nx(t+1) prefetch — retires under MFMA/LDS/gate phases
    int tn = (t + 1 < TSTEPS) ? t + 1 : t;
    f32x2 nxz_n = *(const f32x2*)(nxz + (size_t)(tn * BATCH + bb) * HDIM + c0 + 2 * cp);
    f32x2 nxh_n = *(const f32x2*)(nxh + (size_t)(tn * BATCH + bb) * HDIM + c0 + 2 * cp);

    // ---- MFMA with inline tag-strip repack: both gates, hi+lo W
    f32x4 az0 = z4, az1 = z4, ac0 = z4, ac1 = z4;
#pragma unroll
    for (int kk = 0; kk < 16; ++kk) {
      union { u32 u[4]; bf16x8 v; } a;
#pragma unroll
      for (int j = 0; j < 4; ++j) {
        u64 w = hw[kk * 4 + j];
        a.u[j] = ((u32)(w >> 16) & 0xFFFFu) | ((u32)(w >> 32) & 0xFFFF0000u);
      }
      az0 = __builtin_amdgcn_mfma_f32_16x16x32_bf16(a.v, wz_hi[kk], az0, 0, 0, 0);
      az1 = __builtin_amdgcn_mfma_f32_16x16x32_bf16(a.v, wz_lo[kk], az1, 0, 0, 0);
      ac0 = __builtin_amdgcn_mfma_f32_16x16x32_bf16(a.v, wh_hi[kk], ac0, 0, 0, 0);
      ac1 = __builtin_amdgcn_mfma_f32_16x16x32_bf16(a.v, wh_lo[kk], ac1, 0, 0, 0);
    }
    f32x4 sz = az0 + az1;
    f32x4 sc = ac0 + ac1;

    // D layout: col = lane&15 (= r), row = 4*ko + reg
#pragma unroll
    for (int reg = 0; reg < 4; ++reg) {
      part[0][ksec][half][ko * 4 + reg][r] = sz[reg];
      part[1][ksec][half][ko * 4 + reg][r] = sc[reg];
    }
    __syncthreads();  // sync A: partials visible

    // gate math for the two owned columns
    float zp0 = part[0][0][bh_][br_][2 * cp]     + part[0][1][bh_][br_][2 * cp]     + nxz_c[0];
    float zp1 = part[0][0][bh_][br_][2 * cp + 1] + part[0][1][bh_][br_][2 * cp + 1] + nxz_c[1];
    float cp0 = part[1][0][bh_][br_][2 * cp]     + part[1][1][bh_][br_][2 * cp]     + nxh_c[0];
    float cp1 = part[1][0][bh_][br_][2 * cp + 1] + part[1][1][bh_][br_][2 * cp + 1] + nxh_c[1];
    float zg0 = 1.f / (1.f + __expf(-zp0));
    float zg1 = 1.f / (1.f + __expf(-zp1));
    float cd0 = fmaxf(cp0, 0.f);
    float cd1 = fmaxf(cp1, 0.f);
    float hn0 = zg0 * hr0 + (1.f - zg0) * cd0;
    float hn1 = zg1 * hr1 + (1.f - zg1) * cd1;
    hr0 = hn0; hr1 = hn1;
    __syncthreads();  // sync end: part reads done before next step's writes

    u16 hi0 = f2bf(hn0), hi1 = f2bf(hn1);
    u32 pk = (u32)hi0 | ((u32)hi1 << 16);

    // output stores (fire-and-forget; no drain anywhere)
    if (hs_f) {
      f32x2 o = {hn0, hn1};
      *(f32x2*)(hs_f + (size_t)(t * BATCH + bb) * HDIM + c0 + 2 * cp) = o;
    } else {
      size_t row = (size_t)(t * BATCH + bb) * KP;
      *(u32*)(hs_bf + row + c0 + 2 * cp) = pk;
      u32 plo = (u32)f2bf(hn0 - bf2f(hi0)) | ((u32)f2bf(hn1 - bf2f(hi1)) << 16);
      *(u32*)(hs_bf + row + 1024 + c0 + 2 * cp) = plo;
    }

    if (t == TSTEPS - 1) {
      f32x2 o = {hn0, hn1};
      *(f32x2*)(hlast + (size_t)bb * HDIM + c0 + 2 * cp) = o;
    } else {
      // buffer-reuse guard: all waves must have read h(t-1) (rflag >= t)
      // before we overwrite its slot with h(t+1). Early-loaded values
      // normally satisfy this (posted one full step ago).
      if (t > 0) {
        u32 tgt = (u32)t;
        u32 m = min(min((u32)fa, (u32)(fa >> 32)), min((u32)fb, (u32)(fb >> 32)));
        while (!__all(m >= tgt)) {
          fa = __hip_atomic_load(f64 + lane * 2,     __ATOMIC_RELAXED, __HIP_MEMORY_SCOPE_AGENT);
          fb = __hip_atomic_load(f64 + lane * 2 + 1, __ATOMIC_RELAXED, __HIP_MEMORY_SCOPE_AGENT);
          m = min(min((u32)fa, (u32)(fa >> 32)), min((u32)fb, (u32)(fb >> 32)));
        }
      }
      // tagged h(t+1) broadcast — visibility via tags, no drain/flag needed
      u32 ntag = tag + 1;
      u32 lo = ((u32)hi0 << 16) | ntag;
      u32 hi = ((u32)hi1 << 16) | ntag;
      u64 w = ((u64)hi << 32) | (u64)lo;
      __hip_atomic_store(hbn + (size_t)bb * 512 + g * 8 + cp, w,
                         __ATOMIC_RELAXED, __HIP_MEMORY_SCOPE_AGENT);
    }
    nxz_c = nxz_n; nxh_c = nxh_n;
  }
}

// ---------------- host
extern "C" void kernel_launch(void* const* d_in, const int* in_sizes, int n_in,
                              void* d_out, int out_size, void* d_ws, size_t ws_size,
                              hipStream_t stream) {
  const float* x   = (const float*)d_in[0];
  const float* h0  = (const float*)d_in[1];
  const float* Wxz = (const float*)d_in[2];
  // d_in[3] = bxz: cancels inside BatchNorm -> unused
  const float* gz  = (const float*)d_in[4];
  const float* bz  = (const float*)d_in[5];
  const float* Whz = (const float*)d_in[6];
  const float* bhz = (const float*)d_in[7];
  const float* Wxh = (const float*)d_in[8];
  // d_in[9] = bxh: cancels in BN -> unused
  const float* gh  = (const float*)d_in[10];
  const float* bh  = (const float*)d_in[11];
  const float* Whh = (const float*)d_in[12];
  const float* bhh = (const float*)d_in[13];

  float* out_x = (float*)d_out;
  float* out_h = out_x + (size_t)MROWS * HDIM;

  char* w = (char*)d_ws;
  u16* xsp = (u16*)w;  w += (size_t)MROWS * KP * 2;            // 64 MB
  u16* wxp[4];
  for (int i = 0; i < 4; ++i) { wxp[i] = (u16*)w; w += (size_t)HDIM * KP * 2; }  // 4x4MB
  float* Pz = (float*)w;  w += (size_t)MROWS * HDIM * 4;       // 64 MB
  float* Ph = (float*)w;  w += (size_t)MROWS * HDIM * 4;       // 64 MB
  u64* hbuf = (u64*)w;    w += (size_t)2 * HBUFN * 8;          // 256 KB tagged
  u32* rflags = (u32*)w;  w += 256 * 4;

  cast_split<<<(MROWS * HDIM + 255) / 256, 256, 0, stream>>>(x, xsp, MROWS * HDIM);
  for (int l = 0; l < 2; ++l) {
    cast_split<<<(HDIM * HDIM + 255) / 256, 256, 0, stream>>>(Wxz + (size_t)l * HDIM * HDIM, wxp[l * 2 + 0], HDIM * HDIM);
    cast_split<<<(HDIM * HDIM + 255) / 256, 256, 0, stream>>>(Wxh + (size_t)l * HDIM * HDIM, wxp[l * 2 + 1], HDIM * HDIM);
  }

  for (int l = 0; l < 2; ++l) {
    dim3 gg(HDIM / 128, MROWS / 128, 2);
    gemm_bt<<<gg, 256, 0, stream>>>(xsp, wxp[l * 2 + 0], wxp[l * 2 + 1], Pz, Ph);
    bn_inplace<<<dim3((TSTEPS * HDIM) / 256, 2), 256, 0, stream>>>(
        Pz, Ph,
        gz + (size_t)l * HDIM, bz + (size_t)l * HDIM, bhz + (size_t)l * HDIM,
        gh + (size_t)l * HDIM, bh + (size_t)l * HDIM, bhh + (size_t)l * HDIM);
    init_bar<<<1, 256, 0, stream>>>(rflags);
    ligru_rec<<<NWG, 256, 0, stream>>>(
        Pz, Ph,
        Whz + (size_t)l * HDIM * HDIM, Whh + (size_t)l * HDIM * HDIM, h0,
        (l == 0) ? xsp : (u16*)nullptr,
        (l == 0) ? (float*)nullptr : out_x,
        out_h + (size_t)l * BATCH * HDIM,
        hbuf, rflags, l * 1024);
  }
}

// Round 12
// 6788.984 us; speedup vs baseline: 2.0709x; 2.0709x over previous
//
#include <hip/hip_runtime.h>

// liGRU (2-layer) on MI355X — REVERT to the verified round-3/4 configuration
// (best measured: e2e 6.82 ms, ligru_rec 3248 us x2, absmax 0.03125).
//   1. cast/split inputs to [hi|lo] bf16 along K (split-bf16 => ~fp32 accuracy)
//   2. gemm_bt: C[m,n] = sum_k A[m,k]*W[n,k] via mfma_f32_16x16x32_bf16, K'=2048
//   3. bn_inplace: BatchNorm over batch per (t,h); input biases cancel in BN,
//      recurrent biases folded into beta.
//   4. ligru_rec: persistent kernel, 64 WGs x 256 threads (4 waves, 1 WG/CU),
//      recurrent weights ENTIRELY in registers/AGPRs (1 wave/SIMD -> 512-reg
//      budget), each wave computes BOTH gates from one h-load set (halves LLC
//      burst), fence-free flag barrier, all-wave poll, 2 syncthreads/step.
// History: r5 (per-wave flags), r6 (drain-free sched), r7 (tagged spin) all
// regressed; r8-r11 (layer-pipelined fused kernel) failed numerics ~0.3 4x.
// This structure is the verified local optimum of the sync protocol.

typedef unsigned short u16;
typedef unsigned int   u32;
typedef unsigned long long u64;
typedef __attribute__((ext_vector_type(8))) short bf16x8;
typedef __attribute__((ext_vector_type(4))) float f32x4;
typedef __attribute__((ext_vector_type(2))) float f32x2;

#define TSTEPS 512
#define BATCH  32
#define HDIM   1024
#define MROWS  (TSTEPS * BATCH)   // 16384
#define KP     2048               // split-K (hi|lo concat)
#define NWG    64

__device__ __forceinline__ u16 f2bf(float f) {
  u32 u = __float_as_uint(f);
  return (u16)((u + 0x7FFFu + ((u >> 16) & 1u)) >> 16);  // RNE
}
__device__ __forceinline__ float bf2f(u16 h) {
  return __uint_as_float(((u32)h) << 16);
}

// ---------------- cast + split: fp32 [rows][1024] -> bf16 [rows][2048] = [hi|lo]
__global__ void cast_split(const float* __restrict__ src, u16* __restrict__ dst, int total) {
  int idx = blockIdx.x * 256 + threadIdx.x;
  if (idx >= total) return;
  int m = idx >> 10, k = idx & 1023;
  float v = src[idx];
  u16 hi = f2bf(v);
  u16 lo = f2bf(v - bf2f(hi));
  dst[(size_t)m * KP + k] = hi;
  dst[(size_t)m * KP + 1024 + k] = lo;
}

// ---------------- async global->LDS, 16B per lane
__device__ __forceinline__ void stage16(const u16* g, u16* l) {
  __builtin_amdgcn_global_load_lds((const __attribute__((address_space(1))) u32*)g,
                                   (__attribute__((address_space(3))) u32*)l, 16, 0, 0);
}

// ---------------- GEMM: C[m,n] = sum_k A[m,k] * W[n,k]   (A:[M][KP], W:[1024][KP])
__global__ __launch_bounds__(256) void gemm_bt(
    const u16* __restrict__ A,
    const u16* __restrict__ Wa, const u16* __restrict__ Wb,
    float* __restrict__ Ca, float* __restrict__ Cb) {
  constexpr int BK = 64;
  const u16* W = blockIdx.z ? Wb : Wa;
  float*     C = blockIdx.z ? Cb : Ca;
  const int m0 = blockIdx.y * 128;
  const int n0 = blockIdx.x * 128;
  __shared__ __align__(16) u16 As[128 * BK];
  __shared__ __align__(16) u16 Bs[128 * BK];
  const int tid  = threadIdx.x;
  const int lane = tid & 63;
  const int wv   = tid >> 6;
  const int wm   = wv >> 1, wn = wv & 1;
  const int srow = tid >> 3;
  const int scol = (tid & 7) * 8;
  const int frow = lane & 15;
  const int kcol = (lane >> 4) * 8;

  f32x4 z4 = {0.f, 0.f, 0.f, 0.f};
  f32x4 acc[4][4];
#pragma unroll
  for (int i = 0; i < 4; ++i)
#pragma unroll
    for (int j = 0; j < 4; ++j) acc[i][j] = z4;

  for (int k0 = 0; k0 < KP; k0 += BK) {
#pragma unroll
    for (int i = 0; i < 4; ++i)
      stage16(A + (size_t)(m0 + i * 32 + srow) * KP + k0 + scol, &As[(i * 32 + srow) * BK + scol]);
#pragma unroll
    for (int i = 0; i < 4; ++i)
      stage16(W + (size_t)(n0 + i * 32 + srow) * KP + k0 + scol, &Bs[(i * 32 + srow) * BK + scol]);
    __syncthreads();
#pragma unroll
    for (int kk = 0; kk < 2; ++kk) {
      bf16x8 av[4], bv[4];
#pragma unroll
      for (int i = 0; i < 4; ++i)
        av[i] = *(const bf16x8*)&As[(wm * 64 + i * 16 + frow) * BK + kk * 32 + kcol];
#pragma unroll
      for (int j = 0; j < 4; ++j)
        bv[j] = *(const bf16x8*)&Bs[(wn * 64 + j * 16 + frow) * BK + kk * 32 + kcol];
#pragma unroll
      for (int i = 0; i < 4; ++i)
#pragma unroll
        for (int j = 0; j < 4; ++j)
          acc[i][j] = __builtin_amdgcn_mfma_f32_16x16x32_bf16(av[i], bv[j], acc[i][j], 0, 0, 0);
    }
    __syncthreads();
  }
#pragma unroll
  for (int i = 0; i < 4; ++i)
#pragma unroll
    for (int j = 0; j < 4; ++j) {
      int n  = n0 + wn * 64 + j * 16 + (lane & 15);
      int mb = m0 + wm * 64 + i * 16 + (lane >> 4) * 4;
#pragma unroll
      for (int r = 0; r < 4; ++r)
        C[(size_t)(mb + r) * HDIM + n] = acc[i][j][r];
    }
}

// ---------------- BatchNorm over batch axis, per (t,h); in-place; beta' = beta + b_rec
__global__ void bn_inplace(float* __restrict__ Pz, float* __restrict__ Ph,
                           const float* __restrict__ gz, const float* __restrict__ bz, const float* __restrict__ bhz,
                           const float* __restrict__ gh, const float* __restrict__ bh, const float* __restrict__ bhh) {
  float*       P    = blockIdx.y ? Ph  : Pz;
  const float* gam  = blockIdx.y ? gh  : gz;
  const float* bet  = blockIdx.y ? bh  : bz;
  const float* brec = blockIdx.y ? bhh : bhz;
  int idx = blockIdx.x * 256 + threadIdx.x;
  int h = idx & 1023;
  size_t base = (size_t)(idx >> 10) * (BATCH * HDIM) + h;
  float v[BATCH];
  float s = 0.f;
#pragma unroll
  for (int b = 0; b < BATCH; ++b) { v[b] = P[base + (size_t)b * HDIM]; s += v[b]; }
  float mean = s * (1.f / BATCH);
  float q = 0.f;
#pragma unroll
  for (int b = 0; b < BATCH; ++b) { float d = v[b] - mean; q += d * d; }
  float inv = rsqrtf(q * (1.f / BATCH) + 1e-5f) * gam[h];
  float add = bet[h] + brec[h];
#pragma unroll
  for (int b = 0; b < BATCH; ++b)
    P[base + (size_t)b * HDIM] = (v[b] - mean) * inv + add;
}

__global__ void init_bar(u32* flags) { flags[threadIdx.x] = 0; }  // <<<1,64>>>

// ---------------- persistent recurrence: 64 WGs x 256 threads (4 waves), 512 steps
// wave wv: half = wv>>1 (batch half), ksec = wv&1 (K half). Each wave computes
// BOTH gates (z and cand) from ONE set of h fragments; W fragments live in
// registers/AGPRs (loaded once). Cross-WG protocol (fence-free):
//   producer: atomic WT h-stores -> __syncthreads (vmcnt0: h at LLC) ->
//             relaxed flag store.  consumer: relaxed flag poll -> atomic LLC loads.
__global__ __launch_bounds__(256, 1) void ligru_rec(
    const float* __restrict__ nxz, const float* __restrict__ nxh,
    const float* __restrict__ Whz, const float* __restrict__ Whh,
    const float* __restrict__ h0,
    u16*   __restrict__ hs_bf,   // layer-1 out: [16384][2048] split bf16; or null
    float* __restrict__ hs_f,    // layer-2 out: d_out x region; or null
    float* __restrict__ hlast,   // [32][1024]
    u32*   __restrict__ hbufw,   // [2][32][512] u32 (= packed bf16 pairs)
    u32*   __restrict__ flags) {
  const int g    = blockIdx.x;
  const int c0   = g * 16;
  const int tid  = threadIdx.x;
  const int lane = tid & 63;
  const int wv   = tid >> 6;      // 0..3
  const int half = wv >> 1;       // batch half
  const int ksec = wv & 1;        // K half
  const int r    = lane & 15;     // owned column index (B-frag row) / batch row (A-frag)
  const int ko   = lane >> 4;     // k sub-offset

  __shared__ float part[2][2][2][16][17];  // [gate][ksec][half][row][col]

  // ---- W fragments -> registers (one-time). Fragment: lane holds
  // W[c0+r][ksec*512 + ko*8 + kk*32 + 0..7], split hi/lo bf16.
  bf16x8 wz_hi[16], wz_lo[16], wh_hi[16], wh_lo[16];
  {
    const float* zrow = Whz + (size_t)(c0 + r) * HDIM;
    const float* hrow = Whh + (size_t)(c0 + r) * HDIM;
#pragma unroll
    for (int kk = 0; kk < 16; ++kk) {
      int kb = ksec * 512 + ko * 8 + kk * 32;
      f32x4 z0 = *(const f32x4*)(zrow + kb);
      f32x4 z1 = *(const f32x4*)(zrow + kb + 4);
      f32x4 h0v = *(const f32x4*)(hrow + kb);
      f32x4 h1v = *(const f32x4*)(hrow + kb + 4);
      bf16x8 zh, zl, hh, hl;
#pragma unroll
      for (int j = 0; j < 4; ++j) {
        u16 a = f2bf(z0[j]);  zh[j]   = (short)a;  zl[j]   = (short)f2bf(z0[j] - bf2f(a));
        u16 b = f2bf(z1[j]);  zh[4+j] = (short)b;  zl[4+j] = (short)f2bf(z1[j] - bf2f(b));
        u16 c = f2bf(h0v[j]); hh[j]   = (short)c;  hl[j]   = (short)f2bf(h0v[j] - bf2f(c));
        u16 d = f2bf(h1v[j]); hh[4+j] = (short)d;  hl[4+j] = (short)f2bf(h1v[j] - bf2f(d));
      }
      wz_hi[kk] = zh; wz_lo[kk] = zl; wh_hi[kk] = hh; wh_lo[kk] = hl;
    }
  }

  // ---- per-thread h state: (bb = tid>>3, column pair cA=2*cp, cB=2*cp+1)
  const int bb = tid >> 3;    // batch 0..31
  const int cp = tid & 7;     // col pair 0..7
  const int bh_ = bb >> 4, br_ = bb & 15;
  float hr0 = h0[(size_t)bb * HDIM + c0 + 2 * cp];
  float hr1 = h0[(size_t)bb * HDIM + c0 + 2 * cp + 1];
  {
    u32 p = (u32)f2bf(hr0) | ((u32)f2bf(hr1) << 16);
    __hip_atomic_store(hbufw + (size_t)bb * 512 + g * 8 + cp, p,
                       __ATOMIC_RELAXED, __HIP_MEMORY_SCOPE_AGENT);
  }
  __syncthreads();  // drain h0 broadcast stores (vmcnt 0)
  if (tid == 0)
    __hip_atomic_store(&flags[g], 1u, __ATOMIC_RELAXED, __HIP_MEMORY_SCOPE_AGENT);
  {
    for (;;) {
      u32 f = __hip_atomic_load(&flags[lane], __ATOMIC_RELAXED, __HIP_MEMORY_SCOPE_AGENT);
      if (__all(f >= 1u)) break;
    }
  }

  const size_t hb64base = (size_t)(half * 16 + r) * 256 + ksec * 128 + ko * 2;  // u64 units
  f32x4 z4 = {0.f, 0.f, 0.f, 0.f};

  // nx for t=0 (current)
  f32x2 nxz_c = *(const f32x2*)(nxz + (size_t)bb * HDIM + c0 + 2 * cp);
  f32x2 nxh_c = *(const f32x2*)(nxh + (size_t)bb * HDIM + c0 + 2 * cp);

  for (int t = 0; t < TSTEPS; ++t) {
    const u64* hb64 = (const u64*)(hbufw + (size_t)(t & 1) * (BATCH * 512));
    u32*       hbn  = hbufw + (size_t)((t + 1) & 1) * (BATCH * 512);

    // h fragments: 32 u64 agent-scope LLC loads (issued first — in-order retire)
    u64 hw[32];
#pragma unroll
    for (int kk = 0; kk < 16; ++kk) {
      hw[2 * kk]     = __hip_atomic_load(hb64 + hb64base + kk * 8,
                                         __ATOMIC_RELAXED, __HIP_MEMORY_SCOPE_AGENT);
      hw[2 * kk + 1] = __hip_atomic_load(hb64 + hb64base + kk * 8 + 1,
                                         __ATOMIC_RELAXED, __HIP_MEMORY_SCOPE_AGENT);
    }

    // MFMA: both gates, hi+lo W, 4 independent 16-deep chains
    f32x4 az0 = z4, az1 = z4, ac0 = z4, ac1 = z4;
#pragma unroll
    for (int kk = 0; kk < 16; ++kk) {
      union { u64 d[2]; bf16x8 v; } a;
      a.d[0] = hw[2 * kk];
      a.d[1] = hw[2 * kk + 1];
      az0 = __builtin_amdgcn_mfma_f32_16x16x32_bf16(a.v, wz_hi[kk], az0, 0, 0, 0);
      az1 = __builtin_amdgcn_mfma_f32_16x16x32_bf16(a.v, wz_lo[kk], az1, 0, 0, 0);
      ac0 = __builtin_amdgcn_mfma_f32_16x16x32_bf16(a.v, wh_hi[kk], ac0, 0, 0, 0);
      ac1 = __builtin_amdgcn_mfma_f32_16x16x32_bf16(a.v, wh_lo[kk], ac1, 0, 0, 0);
    }
    f32x4 sz = az0 + az1;
    f32x4 sc = ac0 + ac1;

    // D layout: col = lane&15 (= r), row = 4*ko + reg
#pragma unroll
    for (int reg = 0; reg < 4; ++reg) {
      part[0][ksec][half][ko * 4 + reg][r] = sz[reg];
      part[1][ksec][half][ko * 4 + reg][r] = sc[reg];
    }
    __syncthreads();  // sync A: partials visible

    // prefetch nx(t+1) NOW: retires during h-store drain / flag / poll
    int tn = (t + 1 < TSTEPS) ? t + 1 : t;
    f32x2 nxz_n = *(const f32x2*)(nxz + (size_t)(tn * BATCH + bb) * HDIM + c0 + 2 * cp);
    f32x2 nxh_n = *(const f32x2*)(nxh + (size_t)(tn * BATCH + bb) * HDIM + c0 + 2 * cp);

    // gate math for the two owned columns
    float zp0 = part[0][0][bh_][br_][2 * cp]     + part[0][1][bh_][br_][2 * cp]     + nxz_c[0];
    float zp1 = part[0][0][bh_][br_][2 * cp + 1] + part[0][1][bh_][br_][2 * cp + 1] + nxz_c[1];
    float cp0 = part[1][0][bh_][br_][2 * cp]     + part[1][1][bh_][br_][2 * cp]     + nxh_c[0];
    float cp1 = part[1][0][bh_][br_][2 * cp + 1] + part[1][1][bh_][br_][2 * cp + 1] + nxh_c[1];
    float zg0 = 1.f / (1.f + __expf(-zp0));
    float zg1 = 1.f / (1.f + __expf(-zp1));
    float cd0 = fmaxf(cp0, 0.f);
    float cd1 = fmaxf(cp1, 0.f);
    float hn0 = zg0 * hr0 + (1.f - zg0) * cd0;
    float hn1 = zg1 * hr1 + (1.f - zg1) * cd1;
    hr0 = hn0; hr1 = hn1;

    u16 hi0 = f2bf(hn0), hi1 = f2bf(hn1);
    u32 p = (u32)hi0 | ((u32)hi1 << 16);
    __hip_atomic_store(hbn + (size_t)bb * 512 + g * 8 + cp, p,
                       __ATOMIC_RELAXED, __HIP_MEMORY_SCOPE_AGENT);
    __syncthreads();  // sync B: all waves' h stores drained (vmcnt 0) -> at LLC
    if (tid == 0)
      __hip_atomic_store(&flags[g], (u32)(t + 2), __ATOMIC_RELAXED, __HIP_MEMORY_SCOPE_AGENT);

    // output stores AFTER flag (drain during poll)
    if (hs_f) {
      f32x2 o = {hn0, hn1};
      *(f32x2*)(hs_f + (size_t)(t * BATCH + bb) * HDIM + c0 + 2 * cp) = o;
    } else {
      size_t row = (size_t)(t * BATCH + bb) * KP;
      *(u32*)(hs_bf + row + c0 + 2 * cp) = p;
      u32 plo = (u32)f2bf(hn0 - bf2f(hi0)) | ((u32)f2bf(hn1 - bf2f(hi1)) << 16);
      *(u32*)(hs_bf + row + 1024 + c0 + 2 * cp) = plo;
    }

    if (t == TSTEPS - 1) {
      f32x2 o = {hn0, hn1};
      *(f32x2*)(hlast + (size_t)bb * HDIM + c0 + 2 * cp) = o;
    } else {
      u32 tgt = (u32)(t + 2);
      for (;;) {
        u32 f = __hip_atomic_load(&flags[lane], __ATOMIC_RELAXED, __HIP_MEMORY_SCOPE_AGENT);
        if (__all(f >= tgt)) break;
      }
    }
    nxz_c = nxz_n; nxh_c = nxh_n;
  }
}

// ---------------- host
extern "C" void kernel_launch(void* const* d_in, const int* in_sizes, int n_in,
                              void* d_out, int out_size, void* d_ws, size_t ws_size,
                              hipStream_t stream) {
  const float* x   = (const float*)d_in[0];
  const float* h0  = (const float*)d_in[1];
  const float* Wxz = (const float*)d_in[2];
  // d_in[3] = bxz: cancels inside BatchNorm -> unused
  const float* gz  = (const float*)d_in[4];
  const float* bz  = (const float*)d_in[5];
  const float* Whz = (const float*)d_in[6];
  const float* bhz = (const float*)d_in[7];
  const float* Wxh = (const float*)d_in[8];
  // d_in[9] = bxh: cancels in BN -> unused
  const float* gh  = (const float*)d_in[10];
  const float* bh  = (const float*)d_in[11];
  const float* Whh = (const float*)d_in[12];
  const float* bhh = (const float*)d_in[13];

  float* out_x = (float*)d_out;
  float* out_h = out_x + (size_t)MROWS * HDIM;

  char* w = (char*)d_ws;
  u16* xsp = (u16*)w;  w += (size_t)MROWS * KP * 2;            // 64 MB
  u16* wxp[4];
  for (int i = 0; i < 4; ++i) { wxp[i] = (u16*)w; w += (size_t)HDIM * KP * 2; }  // 4x4MB
  float* Pz = (float*)w;  w += (size_t)MROWS * HDIM * 4;       // 64 MB
  float* Ph = (float*)w;  w += (size_t)MROWS * HDIM * 4;       // 64 MB
  u32* hbufw = (u32*)w;   w += (size_t)2 * BATCH * 512 * 4;    // 128 KB
  u32* flags = (u32*)w;   w += 64 * 4;

  cast_split<<<(MROWS * HDIM + 255) / 256, 256, 0, stream>>>(x, xsp, MROWS * HDIM);
  for (int l = 0; l < 2; ++l) {
    cast_split<<<(HDIM * HDIM + 255) / 256, 256, 0, stream>>>(Wxz + (size_t)l * HDIM * HDIM, wxp[l * 2 + 0], HDIM * HDIM);
    cast_split<<<(HDIM * HDIM + 255) / 256, 256, 0, stream>>>(Wxh + (size_t)l * HDIM * HDIM, wxp[l * 2 + 1], HDIM * HDIM);
  }

  for (int l = 0; l < 2; ++l) {
    dim3 gg(HDIM / 128, MROWS / 128, 2);
    gemm_bt<<<gg, 256, 0, stream>>>(xsp, wxp[l * 2 + 0], wxp[l * 2 + 1], Pz, Ph);
    bn_inplace<<<dim3((TSTEPS * HDIM) / 256, 2), 256, 0, stream>>>(
        Pz, Ph,
        gz + (size_t)l * HDIM, bz + (size_t)l * HDIM, bhz + (size_t)l * HDIM,
        gh + (size_t)l * HDIM, bh + (size_t)l * HDIM, bhh + (size_t)l * HDIM);
    init_bar<<<1, 64, 0, stream>>>(flags);
    ligru_rec<<<NWG, 256, 0, stream>>>(
        Pz, Ph,
        Whz + (size_t)l * HDIM * HDIM, Whh + (size_t)l * HDIM * HDIM, h0,
        (l == 0) ? xsp : (u16*)nullptr,
        (l == 0) ? (float*)nullptr : out_x,
        out_h + (size_t)l * BATCH * HDIM,
        hbufw, flags);
  }
}